// Round 6
// baseline (75.437 us; speedup 1.0000x reference)
//
#include <hip/hip_runtime.h>
#include <math.h>

#define EPS 1e-6f

// Input: feat_map [T=32][D=256][H=56][W=56] fp32. float4 view: slice = 784 float4.
//
// loc_reduce: 1024 blocks (32 t x 32 slice-groups of 8 d) x 448 threads (392 active).
//   Thread owns TWO fixed slice positions: posA = tid, posB = tid+392 (independent
//   accumulator sets -> >=4 loads in flight per wave regardless of scheduler).
//   8 d-iterations x 2 streams x 16 B. Epilogue: LDS histogram (224 floats), then
//   224 global atomicAdds into gsums[t][arr][56] (ws, memset 28 KB per launch).
//
// ws: gsums [32][4][56] floats (arr: 0=s1h,1=s2h,2=s1w,3=s2w), 28672 B.
// out: [0]=tot, then log10(ga1)[32*56], ga2, ga3, ga4.

__global__ __launch_bounds__(448) void loc_reduce(const float* __restrict__ f,
                                                  float* __restrict__ gsums) {
    const int t   = blockIdx.x >> 5;
    const int sg  = blockIdx.x & 31;
    const int tid = threadIdx.x;

    __shared__ float ls[224];
    for (int k = tid; k < 224; k += 448) ls[k] = 0.f;

    float a10 = 0.f, a11 = 0.f, a12 = 0.f, a13 = 0.f;
    float a20 = 0.f, a21 = 0.f, a22 = 0.f, a23 = 0.f;
    float b10 = 0.f, b11 = 0.f, b12 = 0.f, b13 = 0.f;
    float b20 = 0.f, b21 = 0.f, b22 = 0.f, b23 = 0.f;

    if (tid < 392) {
        const int posA = tid;
        const int posB = tid + 392;
        const float4* base = reinterpret_cast<const float4*>(f)
                             + (size_t)t * 200704 + (size_t)sg * 8 * 784;
        const float4* pA = base + posA;
        const float4* pB = base + posB;

        #pragma unroll
        for (int d = 0; d < 8; d += 2) {
            float4 xa0 = pA[(size_t)d * 784];
            float4 xb0 = pB[(size_t)d * 784];
            float4 xa1 = pA[(size_t)(d + 1) * 784];
            float4 xb1 = pB[(size_t)(d + 1) * 784];

            a10 += xa0.x; a11 += xa0.y; a12 += xa0.z; a13 += xa0.w;
            a20 += xa0.x * xa0.x; a21 += xa0.y * xa0.y;
            a22 += xa0.z * xa0.z; a23 += xa0.w * xa0.w;

            b10 += xb0.x; b11 += xb0.y; b12 += xb0.z; b13 += xb0.w;
            b20 += xb0.x * xb0.x; b21 += xb0.y * xb0.y;
            b22 += xb0.z * xb0.z; b23 += xb0.w * xb0.w;

            a10 += xa1.x; a11 += xa1.y; a12 += xa1.z; a13 += xa1.w;
            a20 += xa1.x * xa1.x; a21 += xa1.y * xa1.y;
            a22 += xa1.z * xa1.z; a23 += xa1.w * xa1.w;

            b10 += xb1.x; b11 += xb1.y; b12 += xb1.z; b13 += xb1.w;
            b20 += xb1.x * xb1.x; b21 += xb1.y * xb1.y;
            b22 += xb1.z * xb1.z; b23 += xb1.w * xb1.w;
        }
    }

    __syncthreads();  // LDS zero-init done

    if (tid < 392) {
        const int hA = tid / 14,         vA = tid % 14;
        const int hB = (tid + 392) / 14, vB = (tid + 392) % 14;

        atomicAdd(&ls[hA],      a10 + a11 + a12 + a13);
        atomicAdd(&ls[56 + hA], a20 + a21 + a22 + a23);
        atomicAdd(&ls[hB],      b10 + b11 + b12 + b13);
        atomicAdd(&ls[56 + hB], b20 + b21 + b22 + b23);

        atomicAdd(&ls[112 + 4 * vA + 0], a10);
        atomicAdd(&ls[112 + 4 * vA + 1], a11);
        atomicAdd(&ls[112 + 4 * vA + 2], a12);
        atomicAdd(&ls[112 + 4 * vA + 3], a13);
        atomicAdd(&ls[168 + 4 * vA + 0], a20);
        atomicAdd(&ls[168 + 4 * vA + 1], a21);
        atomicAdd(&ls[168 + 4 * vA + 2], a22);
        atomicAdd(&ls[168 + 4 * vA + 3], a23);

        atomicAdd(&ls[112 + 4 * vB + 0], b10);
        atomicAdd(&ls[112 + 4 * vB + 1], b11);
        atomicAdd(&ls[112 + 4 * vB + 2], b12);
        atomicAdd(&ls[112 + 4 * vB + 3], b13);
        atomicAdd(&ls[168 + 4 * vB + 0], b20);
        atomicAdd(&ls[168 + 4 * vB + 1], b21);
        atomicAdd(&ls[168 + 4 * vB + 2], b22);
        atomicAdd(&ls[168 + 4 * vB + 3], b23);
    }
    __syncthreads();

    if (tid < 224) atomicAdd(&gsums[t * 224 + tid], ls[tid]);
}

__global__ __launch_bounds__(64) void loc_finalize(const float* __restrict__ gsums,
                                                   float* __restrict__ out) {
    const int tid  = threadIdx.x;
    const int t    = tid & 31;
    const bool isW = tid >= 32;

    const float* s1 = &gsums[t * 224 + (isW ? 112 : 0)];
    const float* s2 = &gsums[t * 224 + (isW ? 168 : 56)];
    float* osuf = out + 1 + (isW ? 3584 : 0)    + t * 56;  // ga1 / ga3
    float* opre = out + 1 + (isW ? 5376 : 1792) + t * 56;  // ga2 / ga4

    const float n_per = 14336.f;  // D*W == D*H
    float part = 0.f;

    float a1 = 0.f, a2 = 0.f;
    for (int i = 55; i >= 0; --i) {            // suffix
        a1 += s1[i]; a2 += s2[i];
        const float n  = n_per * (float)(56 - i);
        const float ga = sqrtf(a2 + 2.0f * EPS * a1 + (EPS * EPS) * n);
        osuf[i] = log10f(ga);
        part += ga + EPS;
    }
    a1 = 0.f; a2 = 0.f;
    for (int i = 0; i < 56; ++i) {             // prefix
        a1 += s1[i]; a2 += s2[i];
        const float n  = n_per * (float)(i + 1);
        const float ga = sqrtf(a2 + 2.0f * EPS * a1 + (EPS * EPS) * n);
        opre[i] = log10f(ga);
        part += ga + EPS;
    }

    #pragma unroll
    for (int off = 32; off; off >>= 1) part += __shfl_down(part, off);
    if (tid == 0) out[0] = part * (1.0f / 128.0f);  // /T /4
}

extern "C" void kernel_launch(void* const* d_in, const int* in_sizes, int n_in,
                              void* d_out, int out_size, void* d_ws, size_t ws_size,
                              hipStream_t stream) {
    const float* f = (const float*)d_in[0];
    float* out = (float*)d_out;
    float* ws  = (float*)d_ws;

    hipMemsetAsync(d_ws, 0, 7168 * sizeof(float), stream);
    loc_reduce<<<dim3(1024), dim3(448), 0, stream>>>(f, ws);
    loc_finalize<<<dim3(1), dim3(64), 0, stream>>>(ws, out);
}

// Round 7
// 54.675 us; speedup vs baseline: 1.3797x; 1.3797x over previous
//
#include <hip/hip_runtime.h>
#include <math.h>

#define EPS 1e-6f

typedef float f32x4 __attribute__((ext_vector_type(4)));

// Input: feat_map [T=32][D=256][H=56][W=56] fp32. float4 view: 6,422,528 elems;
// per-t region 200704; d-slice 784. 12544 = 16*784.
//
// loc_reduce: 1568 blocks x 256 threads. Thread g = b*256+tid owns t = g/12544,
//   r = g%12544, fixed in-slice pos = r%784 (h=pos/14, v=pos%14); its 16 samples are
//   j = t*200704 + r + 12544*i (d = r/784 + 16i). Loads: 16 inline-asm
//   global_load_dwordx4 issued back-to-back (fire-and-forget), then vmcnt(8) ->
//   accumulate first 8 (8 KB/wave still in flight), vmcnt(0) -> accumulate rest.
//   sched_barrier(0) after each waitcnt (guide rule #18). Epilogue: LDS histogram
//   (224 floats) -> global atomicAdd into gsums[t][arr][56].
//
// ws: gsums [32][4][56] floats (28672 B), memset per launch.
// out: [0]=tot, then log10(ga1)[32*56], ga2, ga3, ga4.

__global__ __launch_bounds__(256) void loc_reduce(const float* __restrict__ f,
                                                  float* __restrict__ gsums) {
    const int b   = blockIdx.x;            // 0..1567
    const int t   = b / 49;                // uniform per block
    const int tid = threadIdx.x;
    const int r   = (b % 49) * 256 + tid;  // 0..12543
    const int pos = r % 784;
    const int h   = pos / 14;
    const int v   = pos % 14;

    const f32x4* p = reinterpret_cast<const f32x4*>(f) + (size_t)t * 200704 + r;

    f32x4 x0, x1, x2, x3, x4, x5, x6, x7;
    f32x4 y0, y1, y2, y3, y4, y5, y6, y7;

#define GL(dst, idx) \
    asm volatile("global_load_dwordx4 %0, %1, off" : "=v"(dst) : "v"(p + (size_t)(idx) * 12544) : "memory")

    GL(x0, 0);  GL(x1, 1);  GL(x2, 2);  GL(x3, 3);
    GL(x4, 4);  GL(x5, 5);  GL(x6, 6);  GL(x7, 7);
    GL(y0, 8);  GL(y1, 9);  GL(y2, 10); GL(y3, 11);
    GL(y4, 12); GL(y5, 13); GL(y6, 14); GL(y7, 15);
#undef GL

    float s10 = 0.f, s11 = 0.f, s12 = 0.f, s13 = 0.f;
    float s20 = 0.f, s21 = 0.f, s22 = 0.f, s23 = 0.f;

#define ACC(B)                                        \
    do {                                              \
        s10 += (B).x; s11 += (B).y;                   \
        s12 += (B).z; s13 += (B).w;                   \
        s20 += (B).x * (B).x; s21 += (B).y * (B).y;   \
        s22 += (B).z * (B).z; s23 += (B).w * (B).w;   \
    } while (0)

    asm volatile("s_waitcnt vmcnt(8)" ::: "memory");
    __builtin_amdgcn_sched_barrier(0);
    ACC(x0); ACC(x1); ACC(x2); ACC(x3);
    ACC(x4); ACC(x5); ACC(x6); ACC(x7);

    asm volatile("s_waitcnt vmcnt(0)" ::: "memory");
    __builtin_amdgcn_sched_barrier(0);
    ACC(y0); ACC(y1); ACC(y2); ACC(y3);
    ACC(y4); ACC(y5); ACC(y6); ACC(y7);
#undef ACC

    __shared__ float ls[224];
    if (tid < 224) ls[tid] = 0.f;
    __syncthreads();

    atomicAdd(&ls[h],      s10 + s11 + s12 + s13);
    atomicAdd(&ls[56 + h], s20 + s21 + s22 + s23);
    atomicAdd(&ls[112 + 4 * v + 0], s10);
    atomicAdd(&ls[112 + 4 * v + 1], s11);
    atomicAdd(&ls[112 + 4 * v + 2], s12);
    atomicAdd(&ls[112 + 4 * v + 3], s13);
    atomicAdd(&ls[168 + 4 * v + 0], s20);
    atomicAdd(&ls[168 + 4 * v + 1], s21);
    atomicAdd(&ls[168 + 4 * v + 2], s22);
    atomicAdd(&ls[168 + 4 * v + 3], s23);
    __syncthreads();

    if (tid < 224) atomicAdd(&gsums[t * 224 + tid], ls[tid]);
}

__global__ __launch_bounds__(64) void loc_finalize(const float* __restrict__ gsums,
                                                   float* __restrict__ out) {
    const int tid  = threadIdx.x;
    const int t    = tid & 31;
    const bool isW = tid >= 32;

    const float* s1 = &gsums[t * 224 + (isW ? 112 : 0)];
    const float* s2 = &gsums[t * 224 + (isW ? 168 : 56)];
    float* osuf = out + 1 + (isW ? 3584 : 0)    + t * 56;  // ga1 / ga3
    float* opre = out + 1 + (isW ? 5376 : 1792) + t * 56;  // ga2 / ga4

    const float n_per = 14336.f;  // D*W == D*H
    float part = 0.f;

    float a1 = 0.f, a2 = 0.f;
    for (int i = 55; i >= 0; --i) {            // suffix
        a1 += s1[i]; a2 += s2[i];
        const float n  = n_per * (float)(56 - i);
        const float ga = sqrtf(a2 + 2.0f * EPS * a1 + (EPS * EPS) * n);
        osuf[i] = log10f(ga);
        part += ga + EPS;
    }
    a1 = 0.f; a2 = 0.f;
    for (int i = 0; i < 56; ++i) {             // prefix
        a1 += s1[i]; a2 += s2[i];
        const float n  = n_per * (float)(i + 1);
        const float ga = sqrtf(a2 + 2.0f * EPS * a1 + (EPS * EPS) * n);
        opre[i] = log10f(ga);
        part += ga + EPS;
    }

    #pragma unroll
    for (int off = 32; off; off >>= 1) part += __shfl_down(part, off);
    if (tid == 0) out[0] = part * (1.0f / 128.0f);  // /T /4
}

extern "C" void kernel_launch(void* const* d_in, const int* in_sizes, int n_in,
                              void* d_out, int out_size, void* d_ws, size_t ws_size,
                              hipStream_t stream) {
    const float* f = (const float*)d_in[0];
    float* out = (float*)d_out;
    float* ws  = (float*)d_ws;

    hipMemsetAsync(d_ws, 0, 7168 * sizeof(float), stream);
    loc_reduce<<<dim3(1568), dim3(256), 0, stream>>>(f, ws);
    loc_finalize<<<dim3(1), dim3(64), 0, stream>>>(ws, out);
}